// Round 5
// baseline (167.452 us; speedup 1.0000x reference)
//
#include <hip/hip_runtime.h>
#include <hip/hip_fp16.h>

#define B_   2
#define T_   256
#define P_   12
#define C_   512
#define H_   8
#define HKV_ 2
#define D_   64
#define S_   (T_ * P_)   // 3072
#define M_   (B_ * S_)   // 6144
#define NQKV 768         // 512 q + 128 k + 128 v

typedef _Float16 half8_t __attribute__((ext_vector_type(8)));
typedef _Float16 half4_t __attribute__((ext_vector_type(4)));
typedef _Float16 half2_t __attribute__((ext_vector_type(2)));
typedef float    float4_t __attribute__((ext_vector_type(4)));

#if __has_builtin(__builtin_amdgcn_exp2f)
#define EXP2(x) __builtin_amdgcn_exp2f(x)
#else
#define EXP2(x) __expf((x) * 0.69314718f)
#endif

#define SOFT_SHIFT 20.0f
#define SOFT_CLAMP2 15.5f
#define QSCALE (0.125f * 1.44269504f)

// direct global -> LDS, 16B per lane; LDS dest = uniform base + lane*16
#define GLDS16(gp, lp)                                                          \
    __builtin_amdgcn_global_load_lds(                                           \
        (const __attribute__((address_space(1))) void*)(gp),                    \
        (__attribute__((address_space(3))) void*)(lp), 16, 0, 0)

// ---------------------------------------------------------------------------
// Kernel 0: prep — cast hs to f16; build transposed f16 weights
// ---------------------------------------------------------------------------
__global__ __launch_bounds__(256) void prep_kernel(
    const float* __restrict__ hs,
    const float* __restrict__ Wq, const float* __restrict__ Wk,
    const float* __restrict__ Wv, const float* __restrict__ Wo,
    _Float16* __restrict__ hs16,      // [M][512]
    _Float16* __restrict__ wcatT,     // [768][512]
    _Float16* __restrict__ woT)       // [512][512]
{
    const int blk = blockIdx.x;
    const int tid = threadIdx.x;

    if (blk < 160) {
        __shared__ __attribute__((aligned(16))) _Float16 Ts[64][72];
        int t, K;
        const float* src; int srcN, col0; _Float16* dst;
        if (blk < 96) { t = blk; K = 512; dst = wcatT;
            int nt = t / 8;
            int kt = t % 8;
            int n0 = nt * 64, k0 = kt * 64;
            if (n0 < 512)      { src = Wq; srcN = 512; col0 = n0; }
            else if (n0 < 640) { src = Wk; srcN = 128; col0 = n0 - 512; }
            else               { src = Wv; srcN = 128; col0 = n0 - 640; }
#pragma unroll
            for (int i = 0; i < 4; ++i) {
                int row = i * 16 + (tid >> 4);
                int cg  = tid & 15;
                float4_t v = *(const float4_t*)(src + (size_t)(k0 + row) * srcN + col0 + cg * 4);
                Ts[cg * 4 + 0][row] = (_Float16)v[0];
                Ts[cg * 4 + 1][row] = (_Float16)v[1];
                Ts[cg * 4 + 2][row] = (_Float16)v[2];
                Ts[cg * 4 + 3][row] = (_Float16)v[3];
            }
            __syncthreads();
#pragma unroll
            for (int i = 0; i < 2; ++i) {
                int seg = i * 256 + tid;
                int row = seg >> 3, s = seg & 7;
                *(half8_t*)(dst + (size_t)(n0 + row) * K + k0 + s * 8) =
                    *(const half8_t*)&Ts[row][s * 8];
            }
        } else { t = blk - 96; K = 512; dst = woT;
            int nt = t / 8, kt = t % 8;
            int n0 = nt * 64, k0 = kt * 64;
#pragma unroll
            for (int i = 0; i < 4; ++i) {
                int row = i * 16 + (tid >> 4);
                int cg  = tid & 15;
                float4_t v = *(const float4_t*)(Wo + (size_t)(k0 + row) * 512 + n0 + cg * 4);
                Ts[cg * 4 + 0][row] = (_Float16)v[0];
                Ts[cg * 4 + 1][row] = (_Float16)v[1];
                Ts[cg * 4 + 2][row] = (_Float16)v[2];
                Ts[cg * 4 + 3][row] = (_Float16)v[3];
            }
            __syncthreads();
#pragma unroll
            for (int i = 0; i < 2; ++i) {
                int seg = i * 256 + tid;
                int row = seg >> 3, s = seg & 7;
                *(half8_t*)(dst + (size_t)(n0 + row) * K + k0 + s * 8) =
                    *(const half8_t*)&Ts[row][s * 8];
            }
        }
    } else {
        int base = (blk - 160) * 4096;
#pragma unroll
        for (int i = 0; i < 16; ++i) {
            int f4 = base + i * 256 + tid;
            float4_t v = *(const float4_t*)(hs + (size_t)f4 * 4);
            half4_t hv;
            hv[0] = (_Float16)v[0]; hv[1] = (_Float16)v[1];
            hv[2] = (_Float16)v[2]; hv[3] = (_Float16)v[3];
            *(half4_t*)(hs16 + (size_t)f4 * 4) = hv;
        }
    }
}

// ---------------------------------------------------------------------------
// Kernel 1: fused QKV GEMM. hs16(M x 512) @ WcatT^T -> q/k/v buffers.
// ---------------------------------------------------------------------------
__global__ __launch_bounds__(256) void qkv_kernel(
    const _Float16* __restrict__ A,      // [M][512]
    const _Float16* __restrict__ WT,     // [768][512]
    const float* __restrict__ pitch,     // [128][64]
    _Float16* __restrict__ qb,           // [B][8][S][64]
    _Float16* __restrict__ kb,           // [B][2][S][64]
    _Float16* __restrict__ vb)           // [B][2][64][S]
{
    const int m0   = blockIdx.x * 64;
    const int n0   = blockIdx.y * 64;
    const int tid  = threadIdx.x;
    const int wave = tid >> 6;
    const int lane = tid & 63;
    const int ln   = lane & 15;
    const int quad = lane >> 4;

    __shared__ __attribute__((aligned(16))) _Float16 As[64][72];
    __shared__ __attribute__((aligned(16))) _Float16 Bs[64][72];

    float4_t acc[4];
#pragma unroll
    for (int nt = 0; nt < 4; ++nt) acc[nt] = (float4_t){0.f, 0.f, 0.f, 0.f};

    const int srow = tid >> 3;
    const int ss   = tid & 7;

    half8_t ar[2], br[2];
#pragma unroll
    for (int i = 0; i < 2; ++i) {
        int row = i * 32 + srow;
        ar[i] = *(const half8_t*)&A [(size_t)(m0 + row) * 512 + ss * 8];
        br[i] = *(const half8_t*)&WT[(size_t)(n0 + row) * 512 + ss * 8];
    }

    for (int k0 = 0; k0 < 512; k0 += 64) {
        __syncthreads();
#pragma unroll
        for (int i = 0; i < 2; ++i) {
            int row = i * 32 + srow;
            *(half8_t*)&As[row][ss * 8] = ar[i];
            *(half8_t*)&Bs[row][ss * 8] = br[i];
        }
        __syncthreads();

        if (k0 + 64 < 512) {
#pragma unroll
            for (int i = 0; i < 2; ++i) {
                int row = i * 32 + srow;
                ar[i] = *(const half8_t*)&A [(size_t)(m0 + row) * 512 + k0 + 64 + ss * 8];
                br[i] = *(const half8_t*)&WT[(size_t)(n0 + row) * 512 + k0 + 64 + ss * 8];
            }
        }

#pragma unroll
        for (int ks = 0; ks < 2; ++ks) {
            half8_t afrag = *(const half8_t*)&As[wave * 16 + ln][ks * 32 + quad * 8];
#pragma unroll
            for (int nt = 0; nt < 4; ++nt) {
                half8_t bfrag = *(const half8_t*)&Bs[nt * 16 + ln][ks * 32 + quad * 8];
                acc[nt] = __builtin_amdgcn_mfma_f32_16x16x32_f16(afrag, bfrag, acc[nt], 0, 0, 0);
            }
        }
    }

    const int bb      = m0 / S_;
    const int s00     = m0 - bb * S_;
    const int sl_base = wave * 16 + quad * 4;
    const int s_base  = s00 + sl_base;
    const int p_base  = s_base % P_;

    if (n0 < 512) {
        const int h = n0 >> 6;
#pragma unroll
        for (int r = 0; r < 4; ++r) {
            int p = p_base + r; if (p >= P_) p -= P_;
            const float* pr = pitch + p * 64;
            size_t rowb = ((size_t)(bb * H_ + h) * S_ + s_base + r) * 64;
#pragma unroll
            for (int nt = 0; nt < 4; ++nt) {
                int dd = nt * 16 + ln;
                float v = (acc[nt][r] + pr[dd]) * QSCALE;
                qb[rowb + dd] = (_Float16)v;
            }
        }
    } else if (n0 < 640) {
        const int h = (n0 - 512) >> 6;
#pragma unroll
        for (int r = 0; r < 4; ++r) {
            int p = p_base + r; if (p >= P_) p -= P_;
            const float* pr = pitch + p * 64;
            size_t rowb = ((size_t)(bb * HKV_ + h) * S_ + s_base + r) * 64;
#pragma unroll
            for (int nt = 0; nt < 4; ++nt) {
                int dd = nt * 16 + ln;
                kb[rowb + dd] = (_Float16)(acc[nt][r] + pr[dd]);
            }
        }
    } else {
        const int h = (n0 - 640) >> 6;
        __syncthreads();
#pragma unroll
        for (int nt = 0; nt < 4; ++nt)
#pragma unroll
            for (int r = 0; r < 4; ++r)
                As[nt * 16 + ln][sl_base + r] = (_Float16)acc[nt][r];
        __syncthreads();
        const int rw = tid >> 2;
        const int c0 = (tid & 3) * 16;
        _Float16* dst = vb + ((size_t)(bb * HKV_ + h) * 64 + rw) * S_ + s00 + c0;
        *(half8_t*)dst       = *(const half8_t*)&As[rw][c0];
        *(half8_t*)(dst + 8) = *(const half8_t*)&As[rw][c0 + 8];
    }
}

// ---------------------------------------------------------------------------
// Kernel 2: flash attention, 8 waves, 128-key tiles, 32q per wave.
// Wave w: qsplit = w&1 (32 q), ksplit = w>>1 (32 keys of each 128-key tile).
// Each kf/vf B-fragment read feeds TWO MFMAs (both q-subtiles): LDS read
// traffic per MFMA halves vs 16q waves.
// Staging via global_load_lds (no ds_writes, no staging VGPRs). LDS is
// LINEAR (Ks[128][64], VT[64][128]); the key-row permutation (P-layout
// trick) and granule-XOR (bank spread) are folded into the per-lane GLOBAL
// source address; reads apply the same XOR. [m173 pattern]
//   Ks row r holds key perm(r) = 32*(r>>5) + 2*(r&15) + ((r>>4)&1),
//   LDS granule g of row r holds global granule g ^ (r&7)  (16B granules).
//   VT row d, granule g holds V granule g ^ (d&7).
// 4-way O/l cross-wave combine at the end (two stages). LDS total 42 KB.
// ---------------------------------------------------------------------------
__global__ __launch_bounds__(512) void attn_kernel(
    const _Float16* __restrict__ qbuf,  // [B][H][S][64]
    const _Float16* __restrict__ kbuf,  // [B][HKV][S][64]
    const _Float16* __restrict__ vtb,   // [B][HKV][64][S]
    _Float16* __restrict__ ob)          // [B*S][512]
{
    const int qblk = blockIdx.x;
    const int bh   = blockIdx.y;
    const int b    = bh >> 3;
    const int h    = bh & 7;
    const int hkv  = h >> 2;
    const int tid  = threadIdx.x;
    const int w    = tid >> 6;          // 0..7
    const int lane = tid & 63;
    const int ln   = lane & 15;
    const int quad = lane >> 4;

    const _Float16* Q  = qbuf + ((size_t)(b * H_ + h)) * S_ * 64;
    const _Float16* K  = kbuf + ((size_t)(b * HKV_ + hkv)) * S_ * 64;
    const _Float16* Vt = vtb  + ((size_t)(b * HKV_ + hkv)) * 64 * S_;

    // flat LDS: Ks[128][64] | VT[64][128] | Ps[8][16][40]
    __shared__ __attribute__((aligned(16))) _Float16 smem[8192 + 8192 + 5120];
    _Float16* Ks = smem;
    _Float16* VT = smem + 8192;
    _Float16* Ps = smem + 16384;

    const int qsplit = w & 1;
    const int ksplit = w >> 1;
    const int qbase  = qblk * 64 + qsplit * 32;
    const int kk0    = ksplit * 32;

    half8_t qfrag[2][2];
#pragma unroll
    for (int sub = 0; sub < 2; ++sub)
#pragma unroll
        for (int ks = 0; ks < 2; ++ks)
            qfrag[sub][ks] = *(const half8_t*)&Q[(size_t)(qbase + sub * 16 + ln) * 64 + ks * 32 + quad * 8];

    float4_t o[2][4];
#pragma unroll
    for (int sub = 0; sub < 2; ++sub)
#pragma unroll
        for (int nt = 0; nt < 4; ++nt) o[sub][nt] = (float4_t){0.f, 0.f, 0.f, 0.f};
    float lr[2][4] = {{0.f,0.f,0.f,0.f},{0.f,0.f,0.f,0.f}};

    // K staging: wave w fills Ks rows [16w, 16w+16), 2 instrs of 8 rows.
    // lane: row = 16w + 8i + (lane>>3), g = lane&7; key = perm(row); gsrc = g ^ (row&7)
    const int l3 = lane >> 3, g8 = lane & 7;
    const int key0 = 32 * (w >> 1) + 2 * l3 + (w & 1);       // perm for i=0 rows
    const int kgof0 = key0 * 64 + (g8 ^ l3) * 8;             // halves
    const int kgof1 = kgof0 + 1024;                          // key+16, same gsrc
    _Float16* ldsK0 = Ks + (w * 16) * 64;

    // V staging: wave w fills VT rows [8w, 8w+8), 2 instrs of 4 rows.
    // lane: d = 8w + 4i + (lane>>4), g = lane&15; gsrc = g ^ (d&7)
    const int l4 = lane >> 4, g16 = lane & 15;
    const size_t vgof0 = (size_t)(8 * w + l4) * S_ + (size_t)((g16 ^ l4) * 8);
    const size_t vgof1 = (size_t)(8 * w + 4 + l4) * S_ + (size_t)((g16 ^ ((4 + l4) & 7)) * 8);
    _Float16* ldsV0 = VT + (8 * w) * 128;

    const int kxor = (ln & 7) << 3;   // read-side granule XOR (halves)

    for (int kt = 0; kt < S_; kt += 128) {
        __syncthreads();                       // all waves done reading prev tile
        GLDS16(K + (size_t)kt * 64 + kgof0, ldsK0);
        GLDS16(K + (size_t)kt * 64 + kgof1, ldsK0 + 512);
        GLDS16(Vt + kt + vgof0, ldsV0);
        GLDS16(Vt + kt + vgof1, ldsV0 + 512);
        asm volatile("s_waitcnt vmcnt(0)" ::: "memory");
        __syncthreads();                       // tile ready

        // QK^T: wave's 32 keys (2 c-tiles), BOTH q-subtiles per kf read.
        float4_t sf[2][2];
#pragma unroll
        for (int sub = 0; sub < 2; ++sub)
#pragma unroll
            for (int c = 0; c < 2; ++c)
                sf[sub][c] = (float4_t){-SOFT_SHIFT, -SOFT_SHIFT, -SOFT_SHIFT, -SOFT_SHIFT};
        __builtin_amdgcn_s_setprio(1);
#pragma unroll
        for (int ks = 0; ks < 2; ++ks) {
#pragma unroll
            for (int c = 0; c < 2; ++c) {
                const int row = kk0 + c * 16 + ln;
                half8_t kf = *(const half8_t*)&Ks[row * 64 + ((ks * 32 + quad * 8) ^ kxor)];
                sf[0][c] = __builtin_amdgcn_mfma_f32_16x16x32_f16(qfrag[0][ks], kf, sf[0][c], 0, 0, 0);
                sf[1][c] = __builtin_amdgcn_mfma_f32_16x16x32_f16(qfrag[1][ks], kf, sf[1][c], 0, 0, 0);
            }
        }
        __builtin_amdgcn_s_setprio(0);

        // softmax per sub; P half2 writes (cols = natural local key 2*ln+c),
        // then pf read to regs (wave-private Ps reused sub0 -> sub1; in-order LDS)
        half8_t pf[2];
        _Float16* psw = Ps + w * 640;
#pragma unroll
        for (int sub = 0; sub < 2; ++sub) {
#pragma unroll
            for (int rr = 0; rr < 4; ++rr) {
                float e0 = EXP2(fminf(sf[sub][0][rr], SOFT_CLAMP2));
                float e1 = EXP2(fminf(sf[sub][1][rr], SOFT_CLAMP2));
                lr[sub][rr] += e0 + e1;
                half2_t w2; w2[0] = (_Float16)e0; w2[1] = (_Float16)e1;
                *(half2_t*)&psw[(quad * 4 + rr) * 40 + 2 * ln] = w2;
            }
            pf[sub] = *(const half8_t*)&psw[ln * 40 + quad * 8];
        }

        // PV: one vf read feeds BOTH q-subtiles
        __builtin_amdgcn_s_setprio(1);
#pragma unroll
        for (int nt = 0; nt < 4; ++nt) {
            half8_t vf = *(const half8_t*)&VT[(nt * 16 + ln) * 128 + ((kk0 + quad * 8) ^ kxor)];
            o[0][nt] = __builtin_amdgcn_mfma_f32_16x16x32_f16(pf[0], vf, o[0][nt], 0, 0, 0);
            o[1][nt] = __builtin_amdgcn_mfma_f32_16x16x32_f16(pf[1], vf, o[1][nt], 0, 0, 0);
        }
        __builtin_amdgcn_s_setprio(0);
    }

    // ---- epilogue: 4-way k-split combine (two stages), then normalize ----
    // reduce lr over ln within wave (16 lanes share one q)
#pragma unroll
    for (int sub = 0; sub < 2; ++sub)
#pragma unroll
        for (int rr = 0; rr < 4; ++rr) {
            float l = lr[sub][rr];
            l += __shfl_xor(l, 1);
            l += __shfl_xor(l, 2);
            l += __shfl_xor(l, 4);
            l += __shfl_xor(l, 8);
            lr[sub][rr] = l;
        }

    __syncthreads();                           // main-loop LDS reads complete
    float* smemF = (float*)smem;               // Ks+VT region: 8192 floats
    float* Lb    = smemF + 8192;               // Ps region: 256 floats used
    if (ln == 0) {
#pragma unroll
        for (int sub = 0; sub < 2; ++sub)
#pragma unroll
            for (int rr = 0; rr < 4; ++rr)
                Lb[w * 32 + sub * 16 + quad * 4 + rr] = lr[sub][rr];
    }
    // stage A: waves 4..7 dump O (slot layout [idx8][lane][4] -> conflict-free)
    if (w >= 4) {
        float* od = smemF + (w - 4) * 2048;
#pragma unroll
        for (int sub = 0; sub < 2; ++sub)
#pragma unroll
            for (int nt = 0; nt < 4; ++nt)
                *(float4_t*)&od[(sub * 4 + nt) * 256 + lane * 4] = o[sub][nt];
    }
    __syncthreads();
    if (w < 4) {
        const float* os = smemF + w * 2048;
#pragma unroll
        for (int sub = 0; sub < 2; ++sub)
#pragma unroll
            for (int nt = 0; nt < 4; ++nt)
                o[sub][nt] += *(const float4_t*)&os[(sub * 4 + nt) * 256 + lane * 4];
    }
    __syncthreads();
    // stage B: waves 2,3 dump combined halves
    if (w == 2 || w == 3) {
        float* od = smemF + (w - 2) * 2048;
#pragma unroll
        for (int sub = 0; sub < 2; ++sub)
#pragma unroll
            for (int nt = 0; nt < 4; ++nt)
                *(float4_t*)&od[(sub * 4 + nt) * 256 + lane * 4] = o[sub][nt];
    }
    __syncthreads();
    if (w < 2) {
        const float* os = smemF + w * 2048;
#pragma unroll
        for (int sub = 0; sub < 2; ++sub) {
#pragma unroll
            for (int rr = 0; rr < 4; ++rr) {
                int idx = sub * 16 + quad * 4 + rr;
                float l = Lb[w * 32 + idx] + Lb[(w + 2) * 32 + idx]
                        + Lb[(w + 4) * 32 + idx] + Lb[(w + 6) * 32 + idx];
                float inv = 1.0f / l;
                int qg = qbase + sub * 16 + quad * 4 + rr;
                size_t base = ((size_t)(b * S_ + qg)) * 512 + h * 64;
#pragma unroll
                for (int nt = 0; nt < 4; ++nt) {
                    float vsum = o[sub][nt][rr]
                               + os[(sub * 4 + nt) * 256 + lane * 4 + rr];
                    ob[base + nt * 16 + ln] = (_Float16)(vsum * inv);
                }
            }
        }
    }
}

// ---------------------------------------------------------------------------
// Kernel 3: O(f16, M x 512) @ Wo -> fp32 out, using pre-transposed woT f16.
// ---------------------------------------------------------------------------
__global__ __launch_bounds__(256) void proj_out_kernel(
    const _Float16* __restrict__ A,      // [M][512]
    const _Float16* __restrict__ WT,     // [512][512]
    float* __restrict__ outp)            // [M][512]
{
    const int m0   = blockIdx.x * 64;
    const int n0   = blockIdx.y * 64;
    const int tid  = threadIdx.x;
    const int wave = tid >> 6;
    const int lane = tid & 63;
    const int ln   = lane & 15;
    const int quad = lane >> 4;

    __shared__ __attribute__((aligned(16))) _Float16 As[64][72];
    __shared__ __attribute__((aligned(16))) _Float16 Bs[64][72];

    float4_t acc[4];
#pragma unroll
    for (int nt = 0; nt < 4; ++nt) acc[nt] = (float4_t){0.f, 0.f, 0.f, 0.f};

    const int srow = tid >> 3;
    const int ss   = tid & 7;

    half8_t ar[2], br[2];
#pragma unroll
    for (int i = 0; i < 2; ++i) {
        int row = i * 32 + srow;
        ar[i] = *(const half8_t*)&A [(size_t)(m0 + row) * 512 + ss * 8];
        br[i] = *(const half8_t*)&WT[(size_t)(n0 + row) * 512 + ss * 8];
    }

    for (int k0 = 0; k0 < 512; k0 += 64) {
        __syncthreads();
#pragma unroll
        for (int i = 0; i < 2; ++i) {
            int row = i * 32 + srow;
            *(half8_t*)&As[row][ss * 8] = ar[i];
            *(half8_t*)&Bs[row][ss * 8] = br[i];
        }
        __syncthreads();

        if (k0 + 64 < 512) {
#pragma unroll
            for (int i = 0; i < 2; ++i) {
                int row = i * 32 + srow;
                ar[i] = *(const half8_t*)&A [(size_t)(m0 + row) * 512 + k0 + 64 + ss * 8];
                br[i] = *(const half8_t*)&WT[(size_t)(n0 + row) * 512 + k0 + 64 + ss * 8];
            }
        }

#pragma unroll
        for (int ks = 0; ks < 2; ++ks) {
            half8_t afrag = *(const half8_t*)&As[wave * 16 + ln][ks * 32 + quad * 8];
#pragma unroll
            for (int nt = 0; nt < 4; ++nt) {
                half8_t bfrag = *(const half8_t*)&Bs[nt * 16 + ln][ks * 32 + quad * 8];
                acc[nt] = __builtin_amdgcn_mfma_f32_16x16x32_f16(afrag, bfrag, acc[nt], 0, 0, 0);
            }
        }
    }

#pragma unroll
    for (int nt = 0; nt < 4; ++nt) {
        int n = n0 + nt * 16 + ln;
#pragma unroll
        for (int r = 0; r < 4; ++r) {
            int m = m0 + wave * 16 + quad * 4 + r;
            outp[(size_t)m * 512 + n] = acc[nt][r];
        }
    }
}

// ---------------------------------------------------------------------------
extern "C" void kernel_launch(void* const* d_in, const int* in_sizes, int n_in,
                              void* d_out, int out_size, void* d_ws, size_t ws_size,
                              hipStream_t stream) {
    const float* hs    = (const float*)d_in[0];
    const float* Wq    = (const float*)d_in[1];
    const float* Wk    = (const float*)d_in[2];
    const float* Wv    = (const float*)d_in[3];
    const float* Wo    = (const float*)d_in[4];
    const float* pitch = (const float*)d_in[5];
    float* out = (float*)d_out;

    // ws layout (f16 elements). o_buf aliases hs16 (hs16 dead after qkv_kernel).
    _Float16* hs16  = (_Float16*)d_ws;                           // M*512 = 3,145,728
    _Float16* o_buf = hs16;                                      // alias
    _Float16* q_buf = hs16 + (size_t)M_ * 512;                   // 3,145,728
    _Float16* k_buf = q_buf + (size_t)B_ * H_ * S_ * 64;         //   786,432
    _Float16* v_buf = k_buf + (size_t)B_ * HKV_ * S_ * 64;       //   786,432
    _Float16* wcatT = v_buf + (size_t)B_ * HKV_ * S_ * 64;       //   393,216
    _Float16* woT   = wcatT + (size_t)NQKV * 512;                //   262,144

    prep_kernel<<<352, 256, 0, stream>>>(hs, Wq, Wk, Wv, Wo, hs16, wcatT, woT);
    qkv_kernel<<<dim3(M_ / 64, NQKV / 64), 256, 0, stream>>>(hs16, wcatT, pitch, q_buf, k_buf, v_buf);
    attn_kernel<<<dim3(S_ / 64, B_ * H_), 512, 0, stream>>>(q_buf, k_buf, v_buf, o_buf);
    proj_out_kernel<<<dim3(M_ / 64, 8), 256, 0, stream>>>(o_buf, woT, out);
}

// Round 6
// 159.919 us; speedup vs baseline: 1.0471x; 1.0471x over previous
//
#include <hip/hip_runtime.h>
#include <hip/hip_fp16.h>

#define B_   2
#define T_   256
#define P_   12
#define C_   512
#define H_   8
#define HKV_ 2
#define D_   64
#define S_   (T_ * P_)   // 3072
#define M_   (B_ * S_)   // 6144
#define NQKV 768         // 512 q + 128 k + 128 v

typedef _Float16 half8_t __attribute__((ext_vector_type(8)));
typedef _Float16 half4_t __attribute__((ext_vector_type(4)));
typedef _Float16 half2_t __attribute__((ext_vector_type(2)));
typedef float    float4_t __attribute__((ext_vector_type(4)));

#if __has_builtin(__builtin_amdgcn_exp2f)
#define EXP2(x) __builtin_amdgcn_exp2f(x)
#else
#define EXP2(x) __expf((x) * 0.69314718f)
#endif

#define SOFT_SHIFT 20.0f
#define SOFT_CLAMP2 15.5f
#define QSCALE (0.125f * 1.44269504f)

// ---------------------------------------------------------------------------
// Kernel 0: prep — cast hs to f16; build transposed f16 weights
// ---------------------------------------------------------------------------
__global__ __launch_bounds__(256) void prep_kernel(
    const float* __restrict__ hs,
    const float* __restrict__ Wq, const float* __restrict__ Wk,
    const float* __restrict__ Wv, const float* __restrict__ Wo,
    _Float16* __restrict__ hs16,      // [M][512]
    _Float16* __restrict__ wcatT,     // [768][512]
    _Float16* __restrict__ woT)       // [512][512]
{
    const int blk = blockIdx.x;
    const int tid = threadIdx.x;

    if (blk < 160) {
        __shared__ __attribute__((aligned(16))) _Float16 Ts[64][72];
        int t, K;
        const float* src; int srcN, col0; _Float16* dst;
        if (blk < 96) { t = blk; K = 512; dst = wcatT;
            int nt = t / 8;
            int kt = t % 8;
            int n0 = nt * 64, k0 = kt * 64;
            if (n0 < 512)      { src = Wq; srcN = 512; col0 = n0; }
            else if (n0 < 640) { src = Wk; srcN = 128; col0 = n0 - 512; }
            else               { src = Wv; srcN = 128; col0 = n0 - 640; }
#pragma unroll
            for (int i = 0; i < 4; ++i) {
                int row = i * 16 + (tid >> 4);
                int cg  = tid & 15;
                float4_t v = *(const float4_t*)(src + (size_t)(k0 + row) * srcN + col0 + cg * 4);
                Ts[cg * 4 + 0][row] = (_Float16)v[0];
                Ts[cg * 4 + 1][row] = (_Float16)v[1];
                Ts[cg * 4 + 2][row] = (_Float16)v[2];
                Ts[cg * 4 + 3][row] = (_Float16)v[3];
            }
            __syncthreads();
#pragma unroll
            for (int i = 0; i < 2; ++i) {
                int seg = i * 256 + tid;
                int row = seg >> 3, s = seg & 7;
                *(half8_t*)(dst + (size_t)(n0 + row) * K + k0 + s * 8) =
                    *(const half8_t*)&Ts[row][s * 8];
            }
        } else { t = blk - 96; K = 512; dst = woT;
            int nt = t / 8, kt = t % 8;
            int n0 = nt * 64, k0 = kt * 64;
#pragma unroll
            for (int i = 0; i < 4; ++i) {
                int row = i * 16 + (tid >> 4);
                int cg  = tid & 15;
                float4_t v = *(const float4_t*)(Wo + (size_t)(k0 + row) * 512 + n0 + cg * 4);
                Ts[cg * 4 + 0][row] = (_Float16)v[0];
                Ts[cg * 4 + 1][row] = (_Float16)v[1];
                Ts[cg * 4 + 2][row] = (_Float16)v[2];
                Ts[cg * 4 + 3][row] = (_Float16)v[3];
            }
            __syncthreads();
#pragma unroll
            for (int i = 0; i < 2; ++i) {
                int seg = i * 256 + tid;
                int row = seg >> 3, s = seg & 7;
                *(half8_t*)(dst + (size_t)(n0 + row) * K + k0 + s * 8) =
                    *(const half8_t*)&Ts[row][s * 8];
            }
        }
    } else {
        int base = (blk - 160) * 4096;
#pragma unroll
        for (int i = 0; i < 16; ++i) {
            int f4 = base + i * 256 + tid;
            float4_t v = *(const float4_t*)(hs + (size_t)f4 * 4);
            half4_t hv;
            hv[0] = (_Float16)v[0]; hv[1] = (_Float16)v[1];
            hv[2] = (_Float16)v[2]; hv[3] = (_Float16)v[3];
            *(half4_t*)(hs16 + (size_t)f4 * 4) = hv;
        }
    }
}

// ---------------------------------------------------------------------------
// Kernel 1: fused QKV GEMM. hs16(M x 512) @ WcatT^T -> q/k/v buffers.
// ---------------------------------------------------------------------------
__global__ __launch_bounds__(256) void qkv_kernel(
    const _Float16* __restrict__ A,      // [M][512]
    const _Float16* __restrict__ WT,     // [768][512]
    const float* __restrict__ pitch,     // [128][64]
    _Float16* __restrict__ qb,           // [B][8][S][64]
    _Float16* __restrict__ kb,           // [B][2][S][64]
    _Float16* __restrict__ vb)           // [B][2][64][S]
{
    const int m0   = blockIdx.x * 64;
    const int n0   = blockIdx.y * 64;
    const int tid  = threadIdx.x;
    const int wave = tid >> 6;
    const int lane = tid & 63;
    const int ln   = lane & 15;
    const int quad = lane >> 4;

    __shared__ __attribute__((aligned(16))) _Float16 As[64][72];
    __shared__ __attribute__((aligned(16))) _Float16 Bs[64][72];

    float4_t acc[4];
#pragma unroll
    for (int nt = 0; nt < 4; ++nt) acc[nt] = (float4_t){0.f, 0.f, 0.f, 0.f};

    const int srow = tid >> 3;
    const int ss   = tid & 7;

    half8_t ar[2], br[2];
#pragma unroll
    for (int i = 0; i < 2; ++i) {
        int row = i * 32 + srow;
        ar[i] = *(const half8_t*)&A [(size_t)(m0 + row) * 512 + ss * 8];
        br[i] = *(const half8_t*)&WT[(size_t)(n0 + row) * 512 + ss * 8];
    }

    for (int k0 = 0; k0 < 512; k0 += 64) {
        __syncthreads();
#pragma unroll
        for (int i = 0; i < 2; ++i) {
            int row = i * 32 + srow;
            *(half8_t*)&As[row][ss * 8] = ar[i];
            *(half8_t*)&Bs[row][ss * 8] = br[i];
        }
        __syncthreads();

        if (k0 + 64 < 512) {
#pragma unroll
            for (int i = 0; i < 2; ++i) {
                int row = i * 32 + srow;
                ar[i] = *(const half8_t*)&A [(size_t)(m0 + row) * 512 + k0 + 64 + ss * 8];
                br[i] = *(const half8_t*)&WT[(size_t)(n0 + row) * 512 + k0 + 64 + ss * 8];
            }
        }

#pragma unroll
        for (int ks = 0; ks < 2; ++ks) {
            half8_t afrag = *(const half8_t*)&As[wave * 16 + ln][ks * 32 + quad * 8];
#pragma unroll
            for (int nt = 0; nt < 4; ++nt) {
                half8_t bfrag = *(const half8_t*)&Bs[nt * 16 + ln][ks * 32 + quad * 8];
                acc[nt] = __builtin_amdgcn_mfma_f32_16x16x32_f16(afrag, bfrag, acc[nt], 0, 0, 0);
            }
        }
    }

    const int bb      = m0 / S_;
    const int s00     = m0 - bb * S_;
    const int sl_base = wave * 16 + quad * 4;
    const int s_base  = s00 + sl_base;
    const int p_base  = s_base % P_;

    if (n0 < 512) {
        const int h = n0 >> 6;
#pragma unroll
        for (int r = 0; r < 4; ++r) {
            int p = p_base + r; if (p >= P_) p -= P_;
            const float* pr = pitch + p * 64;
            size_t rowb = ((size_t)(bb * H_ + h) * S_ + s_base + r) * 64;
#pragma unroll
            for (int nt = 0; nt < 4; ++nt) {
                int dd = nt * 16 + ln;
                float v = (acc[nt][r] + pr[dd]) * QSCALE;
                qb[rowb + dd] = (_Float16)v;
            }
        }
    } else if (n0 < 640) {
        const int h = (n0 - 512) >> 6;
#pragma unroll
        for (int r = 0; r < 4; ++r) {
            int p = p_base + r; if (p >= P_) p -= P_;
            const float* pr = pitch + p * 64;
            size_t rowb = ((size_t)(bb * HKV_ + h) * S_ + s_base + r) * 64;
#pragma unroll
            for (int nt = 0; nt < 4; ++nt) {
                int dd = nt * 16 + ln;
                kb[rowb + dd] = (_Float16)(acc[nt][r] + pr[dd]);
            }
        }
    } else {
        const int h = (n0 - 640) >> 6;
        __syncthreads();
#pragma unroll
        for (int nt = 0; nt < 4; ++nt)
#pragma unroll
            for (int r = 0; r < 4; ++r)
                As[nt * 16 + ln][sl_base + r] = (_Float16)acc[nt][r];
        __syncthreads();
        const int rw = tid >> 2;
        const int c0 = (tid & 3) * 16;
        _Float16* dst = vb + ((size_t)(bb * HKV_ + h) * 64 + rw) * S_ + s00 + c0;
        *(half8_t*)dst       = *(const half8_t*)&As[rw][c0];
        *(half8_t*)(dst + 8) = *(const half8_t*)&As[rw][c0 + 8];
    }
}

// ---------------------------------------------------------------------------
// Kernel 2: flash attention, 8 waves, 128-key tiles, 32q per wave.
// Wave w: qsplit = w&1 (32 q), ksplit = w>>1 (32 keys of the 128-key tile).
// Each kf/vf B-fragment read feeds TWO MFMAs (both q-subtiles) -> per-wave
// LDS issue drops 312 -> 216 cy/tile vs R4 (duration tracked LDS issue
// across R1/R2/R4). Staging = register prefetch (latency hidden; R5's
// global_load_lds + vmcnt(0) exposed L2 latency and regressed).
// Layout: Ks[128][72] key-interleaved rows (r0 swizzle -> P cols natural),
// VT[64][144] natural cols; strides 72/144 halves are bank-uniform for all
// access patterns (verified mod-32 arithmetic, R4-proven).
// Epilogue: two-stage 4-way k-split combine (R5-proven).
// ---------------------------------------------------------------------------
__global__ __launch_bounds__(512) void attn_kernel(
    const _Float16* __restrict__ qbuf,  // [B][H][S][64]
    const _Float16* __restrict__ kbuf,  // [B][HKV][S][64]
    const _Float16* __restrict__ vtb,   // [B][HKV][64][S]
    _Float16* __restrict__ ob)          // [B*S][512]
{
    const int qblk = blockIdx.x;
    const int bh   = blockIdx.y;
    const int b    = bh >> 3;
    const int h    = bh & 7;
    const int hkv  = h >> 2;
    const int tid  = threadIdx.x;
    const int w    = tid >> 6;          // 0..7
    const int lane = tid & 63;
    const int ln   = lane & 15;
    const int quad = lane >> 4;

    const _Float16* Q  = qbuf + ((size_t)(b * H_ + h)) * S_ * 64;
    const _Float16* K  = kbuf + ((size_t)(b * HKV_ + hkv)) * S_ * 64;
    const _Float16* Vt = vtb  + ((size_t)(b * HKV_ + hkv)) * 64 * S_;

    // flat LDS: Ks[128][72] | VT[64][144] | Ps[8][16][40]  = 47104 B
    __shared__ __attribute__((aligned(16))) _Float16 smem[9216 + 9216 + 5120];
    _Float16* Ksf = smem;
    _Float16* VTf = smem + 9216;
    _Float16* Psf = smem + 18432;

    const int qbase = qblk * 64 + (w & 1) * 32;
    const int kk0   = (w >> 1) * 32;

    half8_t qfrag[2][2];
#pragma unroll
    for (int sub = 0; sub < 2; ++sub)
#pragma unroll
        for (int ks = 0; ks < 2; ++ks)
            qfrag[sub][ks] = *(const half8_t*)&Q[(size_t)(qbase + sub * 16 + ln) * 64 + ks * 32 + quad * 8];

    float4_t o[2][4];
#pragma unroll
    for (int sub = 0; sub < 2; ++sub)
#pragma unroll
        for (int nt = 0; nt < 4; ++nt) o[sub][nt] = (float4_t){0.f, 0.f, 0.f, 0.f};
    float lr[2][4] = {{0.f,0.f,0.f,0.f},{0.f,0.f,0.f,0.f}};

    // staging: 2 K segs + 2 V segs per thread (512 threads)
    const int j = tid >> 3, s = tid & 7;        // j: 0..63
    // key-interleave swizzle: row r0(j) holds key j so P cols are natural;
    // swz(j+64) = swz(j)+64.
    const int r0 = ((j & 1) << 4) | ((j >> 5) << 5) | ((j >> 1) & 15);

    half8_t kr0, kr1, vr0, vr1;
    kr0 = *(const half8_t*)&K[(size_t)j * 64 + s * 8];
    kr1 = *(const half8_t*)&K[(size_t)(64 + j) * 64 + s * 8];
    vr0 = *(const half8_t*)&Vt[(size_t)j * S_ + s * 8];
    vr1 = *(const half8_t*)&Vt[(size_t)j * S_ + 64 + s * 8];

    for (int kt = 0; kt < S_; kt += 128) {
        __syncthreads();
        *(half8_t*)&Ksf[r0 * 72 + s * 8]        = kr0;
        *(half8_t*)&Ksf[(r0 + 64) * 72 + s * 8] = kr1;
        *(half8_t*)&VTf[j * 144 + s * 8]        = vr0;
        *(half8_t*)&VTf[j * 144 + 64 + s * 8]   = vr1;
        __syncthreads();

        if (kt + 128 < S_) {
            kr0 = *(const half8_t*)&K[(size_t)(kt + 128 + j) * 64 + s * 8];
            kr1 = *(const half8_t*)&K[(size_t)(kt + 128 + 64 + j) * 64 + s * 8];
            vr0 = *(const half8_t*)&Vt[(size_t)j * S_ + kt + 128 + s * 8];
            vr1 = *(const half8_t*)&Vt[(size_t)j * S_ + kt + 128 + 64 + s * 8];
        }

        // QK^T: wave's 32 keys (rows kk0..kk0+32), BOTH q-subtiles per kf read
        float4_t sf[2][2];
#pragma unroll
        for (int sub = 0; sub < 2; ++sub)
#pragma unroll
            for (int c = 0; c < 2; ++c)
                sf[sub][c] = (float4_t){-SOFT_SHIFT, -SOFT_SHIFT, -SOFT_SHIFT, -SOFT_SHIFT};
        __builtin_amdgcn_s_setprio(1);
#pragma unroll
        for (int ks = 0; ks < 2; ++ks) {
#pragma unroll
            for (int c = 0; c < 2; ++c) {
                half8_t kf = *(const half8_t*)&Ksf[(kk0 + c * 16 + ln) * 72 + ks * 32 + quad * 8];
                sf[0][c] = __builtin_amdgcn_mfma_f32_16x16x32_f16(qfrag[0][ks], kf, sf[0][c], 0, 0, 0);
                sf[1][c] = __builtin_amdgcn_mfma_f32_16x16x32_f16(qfrag[1][ks], kf, sf[1][c], 0, 0, 0);
            }
        }
        __builtin_amdgcn_s_setprio(0);

        // softmax per sub; half2 P writes (cols = natural local key 2*ln+c);
        // pf read back (wave-private region, in-wave LDS ordering)
        half8_t pf[2];
        _Float16* psw = Psf + w * 640;
#pragma unroll
        for (int sub = 0; sub < 2; ++sub) {
#pragma unroll
            for (int rr = 0; rr < 4; ++rr) {
                float e0 = EXP2(fminf(sf[sub][0][rr], SOFT_CLAMP2));
                float e1 = EXP2(fminf(sf[sub][1][rr], SOFT_CLAMP2));
                lr[sub][rr] += e0 + e1;
                half2_t w2; w2[0] = (_Float16)e0; w2[1] = (_Float16)e1;
                *(half2_t*)&psw[(quad * 4 + rr) * 40 + 2 * ln] = w2;
            }
            pf[sub] = *(const half8_t*)&psw[ln * 40 + quad * 8];
        }

        // PV: one vf read feeds BOTH q-subtiles
        __builtin_amdgcn_s_setprio(1);
#pragma unroll
        for (int nt = 0; nt < 4; ++nt) {
            half8_t vf = *(const half8_t*)&VTf[(nt * 16 + ln) * 144 + kk0 + quad * 8];
            o[0][nt] = __builtin_amdgcn_mfma_f32_16x16x32_f16(pf[0], vf, o[0][nt], 0, 0, 0);
            o[1][nt] = __builtin_amdgcn_mfma_f32_16x16x32_f16(pf[1], vf, o[1][nt], 0, 0, 0);
        }
        __builtin_amdgcn_s_setprio(0);
    }

    // ---- epilogue: 4-way k-split combine (two stages), then normalize ----
    // reduce lr over ln within wave (16 ln lanes share one q)
#pragma unroll
    for (int sub = 0; sub < 2; ++sub)
#pragma unroll
        for (int rr = 0; rr < 4; ++rr) {
            float l = lr[sub][rr];
            l += __shfl_xor(l, 1);
            l += __shfl_xor(l, 2);
            l += __shfl_xor(l, 4);
            l += __shfl_xor(l, 8);
            lr[sub][rr] = l;
        }

    __syncthreads();
    float* smemF = (float*)smem;               // 11776 floats available
    float* Lb    = smemF + 8192;               // 256 floats
    if (ln == 0) {
#pragma unroll
        for (int sub = 0; sub < 2; ++sub)
#pragma unroll
            for (int rr = 0; rr < 4; ++rr)
                Lb[w * 32 + sub * 16 + quad * 4 + rr] = lr[sub][rr];
    }
    // stage A: waves 4..7 dump O
    if (w >= 4) {
        float* od = smemF + (w - 4) * 2048;
#pragma unroll
        for (int sub = 0; sub < 2; ++sub)
#pragma unroll
            for (int nt = 0; nt < 4; ++nt)
                *(float4_t*)&od[(sub * 4 + nt) * 256 + lane * 4] = o[sub][nt];
    }
    __syncthreads();
    if (w < 4) {
        const float* os = smemF + w * 2048;
#pragma unroll
        for (int sub = 0; sub < 2; ++sub)
#pragma unroll
            for (int nt = 0; nt < 4; ++nt)
                o[sub][nt] += *(const float4_t*)&os[(sub * 4 + nt) * 256 + lane * 4];
    }
    __syncthreads();
    // stage B: waves 2,3 dump combined halves
    if (w == 2 || w == 3) {
        float* od = smemF + (w - 2) * 2048;
#pragma unroll
        for (int sub = 0; sub < 2; ++sub)
#pragma unroll
            for (int nt = 0; nt < 4; ++nt)
                *(float4_t*)&od[(sub * 4 + nt) * 256 + lane * 4] = o[sub][nt];
    }
    __syncthreads();
    if (w < 2) {
        const float* os = smemF + w * 2048;
#pragma unroll
        for (int sub = 0; sub < 2; ++sub) {
#pragma unroll
            for (int rr = 0; rr < 4; ++rr) {
                int idx = sub * 16 + quad * 4 + rr;
                float l = Lb[w * 32 + idx] + Lb[(w + 2) * 32 + idx]
                        + Lb[(w + 4) * 32 + idx] + Lb[(w + 6) * 32 + idx];
                float inv = 1.0f / l;
                int qg = qbase + sub * 16 + quad * 4 + rr;
                size_t base = ((size_t)(b * S_ + qg)) * 512 + h * 64;
#pragma unroll
                for (int nt = 0; nt < 4; ++nt) {
                    float vsum = o[sub][nt][rr]
                               + os[(sub * 4 + nt) * 256 + lane * 4 + rr];
                    ob[base + nt * 16 + ln] = (_Float16)(vsum * inv);
                }
            }
        }
    }
}

// ---------------------------------------------------------------------------
// Kernel 3: O(f16, M x 512) @ Wo -> fp32 out, using pre-transposed woT f16.
// ---------------------------------------------------------------------------
__global__ __launch_bounds__(256) void proj_out_kernel(
    const _Float16* __restrict__ A,      // [M][512]
    const _Float16* __restrict__ WT,     // [512][512]
    float* __restrict__ outp)            // [M][512]
{
    const int m0   = blockIdx.x * 64;
    const int n0   = blockIdx.y * 64;
    const int tid  = threadIdx.x;
    const int wave = tid >> 6;
    const int lane = tid & 63;
    const int ln   = lane & 15;
    const int quad = lane >> 4;

    __shared__ __attribute__((aligned(16))) _Float16 As[64][72];
    __shared__ __attribute__((aligned(16))) _Float16 Bs[64][72];

    float4_t acc[4];
#pragma unroll
    for (int nt = 0; nt < 4; ++nt) acc[nt] = (float4_t){0.f, 0.f, 0.f, 0.f};

    const int srow = tid >> 3;
    const int ss   = tid & 7;

    half8_t ar[2], br[2];
#pragma unroll
    for (int i = 0; i < 2; ++i) {
        int row = i * 32 + srow;
        ar[i] = *(const half8_t*)&A [(size_t)(m0 + row) * 512 + ss * 8];
        br[i] = *(const half8_t*)&WT[(size_t)(n0 + row) * 512 + ss * 8];
    }

    for (int k0 = 0; k0 < 512; k0 += 64) {
        __syncthreads();
#pragma unroll
        for (int i = 0; i < 2; ++i) {
            int row = i * 32 + srow;
            *(half8_t*)&As[row][ss * 8] = ar[i];
            *(half8_t*)&Bs[row][ss * 8] = br[i];
        }
        __syncthreads();

        if (k0 + 64 < 512) {
#pragma unroll
            for (int i = 0; i < 2; ++i) {
                int row = i * 32 + srow;
                ar[i] = *(const half8_t*)&A [(size_t)(m0 + row) * 512 + k0 + 64 + ss * 8];
                br[i] = *(const half8_t*)&WT[(size_t)(n0 + row) * 512 + k0 + 64 + ss * 8];
            }
        }

#pragma unroll
        for (int ks = 0; ks < 2; ++ks) {
            half8_t afrag = *(const half8_t*)&As[wave * 16 + ln][ks * 32 + quad * 8];
#pragma unroll
            for (int nt = 0; nt < 4; ++nt) {
                half8_t bfrag = *(const half8_t*)&Bs[nt * 16 + ln][ks * 32 + quad * 8];
                acc[nt] = __builtin_amdgcn_mfma_f32_16x16x32_f16(afrag, bfrag, acc[nt], 0, 0, 0);
            }
        }
    }

#pragma unroll
    for (int nt = 0; nt < 4; ++nt) {
        int n = n0 + nt * 16 + ln;
#pragma unroll
        for (int r = 0; r < 4; ++r) {
            int m = m0 + wave * 16 + quad * 4 + r;
            outp[(size_t)m * 512 + n] = acc[nt][r];
        }
    }
}

// ---------------------------------------------------------------------------
extern "C" void kernel_launch(void* const* d_in, const int* in_sizes, int n_in,
                              void* d_out, int out_size, void* d_ws, size_t ws_size,
                              hipStream_t stream) {
    const float* hs    = (const float*)d_in[0];
    const float* Wq    = (const float*)d_in[1];
    const float* Wk    = (const float*)d_in[2];
    const float* Wv    = (const float*)d_in[3];
    const float* Wo    = (const float*)d_in[4];
    const float* pitch = (const float*)d_in[5];
    float* out = (float*)d_out;

    // ws layout (f16 elements). o_buf aliases hs16 (hs16 dead after qkv_kernel).
    _Float16* hs16  = (_Float16*)d_ws;                           // M*512 = 3,145,728
    _Float16* o_buf = hs16;                                      // alias
    _Float16* q_buf = hs16 + (size_t)M_ * 512;                   // 3,145,728
    _Float16* k_buf = q_buf + (size_t)B_ * H_ * S_ * 64;         //   786,432
    _Float16* v_buf = k_buf + (size_t)B_ * HKV_ * S_ * 64;       //   786,432
    _Float16* wcatT = v_buf + (size_t)B_ * HKV_ * S_ * 64;       //   393,216
    _Float16* woT   = wcatT + (size_t)NQKV * 512;                //   262,144

    prep_kernel<<<352, 256, 0, stream>>>(hs, Wq, Wk, Wv, Wo, hs16, wcatT, woT);
    qkv_kernel<<<dim3(M_ / 64, NQKV / 64), 256, 0, stream>>>(hs16, wcatT, pitch, q_buf, k_buf, v_buf);
    attn_kernel<<<dim3(S_ / 64, B_ * H_), 512, 0, stream>>>(q_buf, k_buf, v_buf, o_buf);
    proj_out_kernel<<<dim3(M_ / 64, 8), 256, 0, stream>>>(o_buf, woT, out);
}